// Round 1
// 316.643 us; speedup vs baseline: 1.0307x; 1.0307x over previous
//
#include <hip/hip_runtime.h>
#include <math.h>

// DownConvFace: 3 stages of {mesh_conv -> BN(global stats) -> (+res) -> LeakyReLU(0.2)}
// B=4, F=50000, Cin=32/64/64, O=64, fp32 in/out.
//
// R7: conv kernel is latency-bound on the gather (MfmaUtil 3.7%, HBM 15%, occ 36%).
//  (a) Drop the +8-short LDS pad; XOR-swizzle rows (byte ^= (row&7)<<4) instead.
//      LDS 33792->32768 => 5 blocks/CU instead of 4 (+25% resident waves/MLP).
//  (b) 1-D grid + XCD-chunked bijective remap (lid%8 -> XCD): each XCD gathers
//      from ONE batch (6.4MB) instead of all four (25.6MB) -> L2 hit rate up,
//      duplicate cross-XCD HBM fetches down (FETCH 41.5MB -> ~30MB predicted).
//  (c) norm_kernel vectorized 8B->16B per lane.

typedef __attribute__((ext_vector_type(8))) short short8;
typedef __attribute__((ext_vector_type(8))) unsigned short ushort8_t;
typedef __attribute__((ext_vector_type(4))) float f32x4;

__device__ inline unsigned short f2bf(float v) {
    union { float f; unsigned u; } x; x.f = v;
    unsigned r = x.u + 0x7fffu + ((x.u >> 16) & 1u);   // RNE
    return (unsigned short)(r >> 16);
}
__device__ inline float bf2f(unsigned short u) {
    union { unsigned u; float f; } x; x.u = ((unsigned)u) << 16; return x.f;
}

// fe [B][32][F] fp32 -> fe_t [B][F][32] bf16. grid (ceil(F/64), B), block 256.
__global__ void transpose_fe_kernel(const float* __restrict__ fe,
                                    unsigned short* __restrict__ o, int F)
{
    __shared__ float tile[64 * 33];
    const int b = blockIdx.y;
    const int f0 = blockIdx.x * 64;
    const int t = threadIdx.x;
    const int lane = t & 63;
    const int w = t >> 6;
    const int f = f0 + lane;
    if (f < F) {
#pragma unroll
        for (int i = 0; i < 8; ++i) {
            const int c = w * 8 + i;
            tile[lane * 33 + c] = fe[((size_t)b * 32 + c) * F + f];
        }
    }
    __syncthreads();
    const int j = t >> 2, s = t & 3;
    const int fj = f0 + j;
    if (fj < F) {
        ushort8_t v;
#pragma unroll
        for (int i = 0; i < 8; ++i) v[i] = f2bf(tile[j * 33 + s * 8 + i]);
        *(ushort8_t*)(o + ((size_t)b * F + fj) * 32 + s * 8) = v;
    }
}

// Cast weights fp32->bf16 (flat; [O][C][4] == [O][4C], k=4c+kk).
__global__ void cast_weights_kernel(const float* __restrict__ w1,
                                    const float* __restrict__ w2a,
                                    const float* __restrict__ w2b,
                                    unsigned short* __restrict__ w1b,
                                    unsigned short* __restrict__ w2ab,
                                    unsigned short* __restrict__ w2bb)
{
    const int i = blockIdx.x * blockDim.x + threadIdx.x;
    if (i < 64 * 128) w1b[i] = f2bf(w1[i]);
    if (i < 64 * 256) { w2ab[i] = f2bf(w2a[i]); w2bb[i] = f2bf(w2b[i]); }
}

// Fused mesh-conv GEMM + BN-stats epilogue. Block 256 (4 waves), 64 faces x 64 o.
// 1-D grid = nb = nbx*B blocks, XCD-chunked remap. Y out bf16 [B*F][64];
// per-block stats to pS/pQ [64][nb].
// G LDS: row = K shorts, NO pad (row stride 2K bytes, power of 2);
// XOR swizzle byte ^= ((row&7)<<4). All G accesses are 16B-granular so the
// swizzle is a bijection on 16B chunks; MFMA b128 reads (16 consecutive rows,
// same 64B column) spread over 8 bank-groups per quarter-wave => <=2-way.
// CIN=64: 64*512B = 32768B LDS => 5 blocks/CU (was 4 at 33792).
template <int CIN>
__launch_bounds__(256, 4)
__global__ void conv_mfma_kernel(const unsigned short* __restrict__ x,  // [B][F][CIN] bf16
                                 const int*   __restrict__ gidx,        // [B][F][3]
                                 const unsigned short* __restrict__ wb, // [64][K] bf16
                                 const float* __restrict__ bias,        // [64]
                                 unsigned short* __restrict__ y,        // [B*F][64] bf16
                                 float* __restrict__ pS,                // [64][nb]
                                 float* __restrict__ pQ,                // [64][nb]
                                 int nb, int nbx, int F)
{
    constexpr int K  = 4 * CIN;
    constexpr int RB = 2 * K;                          // row bytes, no pad
    constexpr int GB = 64 * RB;                        // G bytes (16384 / 32768)
    constexpr int SB = (GB > 19456) ? GB : 19456;      // tile(17408)+red(2048)
    __shared__ __align__(16) unsigned char smem[SB];
    float* tile = (float*)smem;                  // [64][68] fp32 (reuses G)
    float* redS = (float*)(smem + 17408);        // [4][64]
    float* redQ = redS + 256;                    // [4][64]

    // ---- XCD-chunked bijective block remap (m204): lid%8 ~ XCD ----
    const int lid = blockIdx.x;
    const int qq = nb >> 3, rr = nb & 7;
    const int xcd = lid & 7, slot = lid >> 3;
    const int work = (xcd < rr ? xcd * (qq + 1)
                               : rr * (qq + 1) + (xcd - rr) * qq) + slot;
    const int b  = work / nbx;
    const int f0 = (work - b * nbx) * 64;
    const int t  = threadIdx.x;

    // ---- phase 1: gather contiguous bf16 rows, build features into LDS ----
    {
        const int j = t >> 2, s = t & 3;         // 4 threads per face
        const int f = f0 + j;
        unsigned char* grow = smem + j * RB;
        const int swz = (j & 7) << 4;
        if (f < F) {
            const unsigned short* xb = x + (size_t)b * F * CIN;
            const int* gp = gidx + ((size_t)b * F + f) * 3;
            const int g0 = gp[0], g1 = gp[1], g2 = gp[2];
            const unsigned short* pc = xb + (size_t)f  * CIN;
            const unsigned short* p0 = xb + (size_t)g0 * CIN;
            const unsigned short* p1 = xb + (size_t)g1 * CIN;
            const unsigned short* p2 = xb + (size_t)g2 * CIN;
#pragma unroll
            for (int i = 0; i < CIN / 32; ++i) {
                const int c0 = (i * 4 + s) * 8;          // 8 channels, 16B loads
                const ushort8_t vc = *(const ushort8_t*)(pc + c0);
                const ushort8_t v0 = *(const ushort8_t*)(p0 + c0);
                const ushort8_t v1 = *(const ushort8_t*)(p1 + c0);
                const ushort8_t v2 = *(const ushort8_t*)(p2 + c0);
                unsigned short feat[32];
#pragma unroll
                for (int q = 0; q < 8; ++q) {
                    const float ctr = bf2f(vc[q]);
                    const float a   = bf2f(v0[q]);
                    const float bb  = bf2f(v1[q]);
                    const float cc  = bf2f(v2[q]);
                    const float su  = a + bb + cc;
                    const float dd  = fabsf(a - bb) + fabsf(bb - cc) + fabsf(cc - a);
                    const float mm  = fmaxf(a, fmaxf(bb, cc));
                    feat[4 * q + 0] = f2bf(ctr);
                    feat[4 * q + 1] = f2bf(su);
                    feat[4 * q + 2] = f2bf(dd);
                    feat[4 * q + 3] = f2bf(mm);
                }
#pragma unroll
                for (int q4 = 0; q4 < 4; ++q4) {        // static indices only
                    const int qb = 8 * c0 + 16 * q4;    // 16B chunk byte offset
                    *(ushort8_t*)(grow + (qb ^ swz)) = *(ushort8_t*)(feat + q4 * 8);
                }
            }
        } else {
            ushort8_t z = {0, 0, 0, 0, 0, 0, 0, 0};
#pragma unroll
            for (int i = 0; i < CIN / 32; ++i) {
                const int c0 = (i * 4 + s) * 8;
#pragma unroll
                for (int q4 = 0; q4 < 4; ++q4) {
                    const int qb = 8 * c0 + 16 * q4;
                    *(ushort8_t*)(grow + (qb ^ swz)) = z;
                }
            }
        }
    }
    __syncthreads();

    // ---- phase 2: MFMA ----
    const int lane = t & 63, wv = t >> 6;
    const int l15 = lane & 15, quad = lane >> 4;
    const int kb = quad * 8;

    f32x4 acc[4];
#pragma unroll
    for (int mt = 0; mt < 4; ++mt) acc[mt] = (f32x4){0.f, 0.f, 0.f, 0.f};

    const int n = wv * 16 + l15;
    unsigned char* nrow = smem + n * RB;
    const int nswz = (n & 7) << 4;
#pragma unroll
    for (int ks = 0; ks < K; ks += 32) {
        const short8 bfr = *(const short8*)(nrow + ((2 * (ks + kb)) ^ nswz));
#pragma unroll
        for (int mt = 0; mt < 4; ++mt) {
            const short8 afr = *(const short8*)(wb + (size_t)(mt * 16 + l15) * K + ks + kb);
            acc[mt] = __builtin_amdgcn_mfma_f32_16x16x32_bf16(afr, bfr, acc[mt], 0, 0, 0);
        }
    }
    __syncthreads();   // G dead; reuse as tile

    // ---- epilogue: acc -> LDS tile [face][68] (+bias), then stats + bf16 store ----
    {
        const int face = wv * 16 + l15;
#pragma unroll
        for (int mt = 0; mt < 4; ++mt) {
            const int ob = mt * 16 + quad * 4;
            const f32x4 b4 = *(const f32x4*)(bias + ob);
            *(f32x4*)(tile + face * 68 + ob) = acc[mt] + b4;
        }
    }
    __syncthreads();
    {   // pass A: per-block channel partial sums (valid faces only)
        const int o = t & 63, g = t >> 6;
        float S = 0.f, Q = 0.f;
#pragma unroll
        for (int i = 0; i < 16; ++i) {
            const int f = g + 4 * i;
            if (f0 + f < F) {
                const float v = tile[f * 68 + o];
                S += v; Q += v * v;
            }
        }
        redS[g * 64 + o] = S;
        redQ[g * 64 + o] = Q;
    }
    {   // pass B: coalesced bf16 Y store
        const int j = t >> 2, seg = t & 3;
        const int f = f0 + j;
        if (f < F) {
            ushort8_t u0, u1;
#pragma unroll
            for (int ii = 0; ii < 8; ++ii) u0[ii] = f2bf(tile[j * 68 + seg * 16 + ii]);
#pragma unroll
            for (int ii = 0; ii < 8; ++ii) u1[ii] = f2bf(tile[j * 68 + seg * 16 + 8 + ii]);
            unsigned short* yp = y + ((size_t)b * F + f) * 64 + seg * 16;
            *(ushort8_t*)yp       = u0;
            *(ushort8_t*)(yp + 8) = u1;
        }
    }
    __syncthreads();
    if (t < 64) {
        const float S = redS[t] + redS[64 + t] + redS[128 + t] + redS[192 + t];
        const float Q = redQ[t] + redQ[64 + t] + redQ[128 + t] + redQ[192 + t];
        pS[(size_t)t * nb + work] = S;     // channel-major: coalesced finalize reads
        pQ[(size_t)t * nb + work] = Q;
    }
}

// grid 64 (one block per channel), 256 threads. Contiguous reads of pS/pQ[o][0..nb).
__global__ void finalize_kernel(const float* __restrict__ pS, const float* __restrict__ pQ,
                                int nb, float invN,
                                const float* __restrict__ gamma,
                                const float* __restrict__ beta,
                                float* __restrict__ mr)
{
    __shared__ float rs_[256], rq_[256];
    const int o = blockIdx.x, t = threadIdx.x;
    float S = 0.f, Q = 0.f;
    for (int j = t; j < nb; j += 256) {
        S += pS[(size_t)o * nb + j];
        Q += pQ[(size_t)o * nb + j];
    }
    rs_[t] = S; rq_[t] = Q;
    __syncthreads();
#pragma unroll
    for (int s = 128; s > 0; s >>= 1) {
        if (t < s) { rs_[t] += rs_[t + s]; rq_[t] += rq_[t + s]; }
        __syncthreads();
    }
    if (t == 0) {
        const float mu  = rs_[0] * invN;
        const float var = rq_[0] * invN - mu * mu;
        const float rsg = rsqrtf(var + 1e-5f);
        const float sc  = gamma[o] * rsg;
        mr[o]      = sc;
        mr[64 + o] = fmaf(-sc, mu, beta[o]);
    }
}

// BN+res+lrelu, face-major bf16 -> bf16. One 16B group of 8 channels per thread.
__global__ void norm_kernel(const unsigned short* __restrict__ y,   // [M][64] bf16
                            const unsigned short* __restrict__ res, // [M][64] bf16 or null
                            const float* __restrict__ mr,
                            unsigned short* __restrict__ out,       // [M][64] bf16
                            int N8)
{
    const int tid = blockIdx.x * blockDim.x + threadIdx.x;
    if (tid >= N8) return;
    const int c0 = (tid & 7) * 8;
    const ushort8_t yv = *(const ushort8_t*)(y + (size_t)tid * 8);
    const f32x4 scA = *(const f32x4*)(mr + c0);
    const f32x4 scB = *(const f32x4*)(mr + c0 + 4);
    const f32x4 shA = *(const f32x4*)(mr + 64 + c0);
    const f32x4 shB = *(const f32x4*)(mr + 64 + c0 + 4);
    float r[8];
#pragma unroll
    for (int i = 0; i < 4; ++i) {
        r[i]     = fmaf(bf2f(yv[i]),     scA[i], shA[i]);
        r[4 + i] = fmaf(bf2f(yv[4 + i]), scB[i], shB[i]);
    }
    if (res) {
        const ushort8_t u = *(const ushort8_t*)(res + (size_t)tid * 8);
#pragma unroll
        for (int i = 0; i < 8; ++i) r[i] += bf2f(u[i]);
    }
    ushort8_t o;
#pragma unroll
    for (int i = 0; i < 8; ++i) {
        const float v = r[i];
        o[i] = f2bf(v >= 0.f ? v : 0.2f * v);
    }
    *(ushort8_t*)(out + (size_t)tid * 8) = o;
}

// Final BN+res+lrelu fused with transpose [B*F][64] -> [B][64][F] fp32 (d_out).
__global__ void norm_transpose_kernel(const unsigned short* __restrict__ y,   // bf16
                                      const unsigned short* __restrict__ res, // bf16
                                      const float* __restrict__ mr,
                                      float* __restrict__ out, int F)
{
    __shared__ float tile[64 * 65];
    const int b = blockIdx.y, f0 = blockIdx.x * 64, t = threadIdx.x;
    const int j = t >> 2, s = t & 3;
    const int f = f0 + j;
    if (f < F) {
        const size_t row = ((size_t)b * F + f) * 64;
#pragma unroll
        for (int i = 0; i < 4; ++i) {
            const int c0 = (i * 4 + s) * 4;
            const ushort4 yv = *(const ushort4*)(y + row + c0);
            const f32x4 sc = *(const f32x4*)(mr + c0);
            const f32x4 sh = *(const f32x4*)(mr + 64 + c0);
            const ushort4 u = *(const ushort4*)(res + row + c0);
            const float yf[4] = {bf2f(yv.x), bf2f(yv.y), bf2f(yv.z), bf2f(yv.w)};
            const float rv[4] = {bf2f(u.x), bf2f(u.y), bf2f(u.z), bf2f(u.w)};
#pragma unroll
            for (int q = 0; q < 4; ++q) {
                float vv = fmaf(yf[q], sc[q], sh[q]) + rv[q];
                vv = vv >= 0.f ? vv : 0.2f * vv;
                tile[(c0 + q) * 65 + j] = vv;
            }
        }
    }
    __syncthreads();
    const int o = t >> 2;
    float* ob = out + ((size_t)b * 64 + o) * F + f0;
#pragma unroll
    for (int i = 0; i < 4; ++i) {
        const int fs = (i * 4 + s) * 4;
        if (f0 + fs < F) {
            f32x4 v;
#pragma unroll
            for (int q = 0; q < 4; ++q) v[q] = tile[o * 65 + fs + q];
            *(f32x4*)(ob + fs) = v;
        }
    }
}

extern "C" void kernel_launch(void* const* d_in, const int* in_sizes, int n_in,
                              void* d_out, int out_size, void* d_ws, size_t ws_size,
                              hipStream_t stream)
{
    const float* fe  = (const float*)d_in[0];
    const int*   gm  = (const int*)d_in[1];
    const float* w1  = (const float*)d_in[2];
    const float* b1  = (const float*)d_in[3];
    const float* w2a = (const float*)d_in[4];
    const float* b2a = (const float*)d_in[5];
    const float* w2b = (const float*)d_in[6];
    const float* b2b = (const float*)d_in[7];
    const float* g0  = (const float*)d_in[8];
    const float* be0 = (const float*)d_in[9];
    const float* g1  = (const float*)d_in[10];
    const float* be1 = (const float*)d_in[11];
    const float* g2  = (const float*)d_in[12];
    const float* be2 = (const float*)d_in[13];

    const int B = 4, O = 64;
    const int F = in_sizes[0] / (B * 32);
    const int M = B * F;
    const float invN = 1.0f / (float)M;
    const int nbx = (F + 63) / 64;
    const int nb  = nbx * B;

    // Workspace: bufY bf16 [M][64] + xbuf bf16 [M][64] + partials + weights.
    unsigned short* bufY = (unsigned short*)d_ws;
    unsigned short* xbuf = bufY + (size_t)M * O;
    float* pS   = (float*)(xbuf + (size_t)M * O);       // [64][nb]
    float* pQ   = pS + (size_t)64 * nb;                 // [64][nb]
    float* mr   = pQ + (size_t)64 * nb;                 // [2][64]
    unsigned short* w1b  = (unsigned short*)(mr + 128); // [64][128]
    unsigned short* w2ab = w1b + 64 * 128;              // [64][256]
    unsigned short* w2bb = w2ab + 64 * 256;             // [64][256]
    unsigned short* fe_t = (unsigned short*)d_out;      // [B][F][32] bf16, dead after conv1

    dim3 blk(256);
    dim3 tgrid(nbx, B);
    const int N8 = M * 8;
    dim3 ngrid((N8 + 255) / 256);

    transpose_fe_kernel<<<tgrid, blk, 0, stream>>>(fe, fe_t, F);
    cast_weights_kernel<<<64, 256, 0, stream>>>(w1, w2a, w2b, w1b, w2ab, w2bb);

    // ---- Stage 1 ----
    conv_mfma_kernel<32><<<nb, blk, 0, stream>>>(fe_t, gm, w1b, b1, bufY, pS, pQ, nb, nbx, F);
    finalize_kernel<<<64, 256, 0, stream>>>(pS, pQ, nb, invN, g0, be0, mr);
    norm_kernel<<<ngrid, blk, 0, stream>>>(bufY, nullptr, mr, xbuf, N8);

    // ---- Stage 2 ----
    conv_mfma_kernel<64><<<nb, blk, 0, stream>>>(xbuf, gm, w2ab, b2a, bufY, pS, pQ, nb, nbx, F);
    finalize_kernel<<<64, 256, 0, stream>>>(pS, pQ, nb, invN, g1, be1, mr);
    norm_kernel<<<ngrid, blk, 0, stream>>>(bufY, xbuf, mr, xbuf, N8);

    // ---- Stage 3 ----
    conv_mfma_kernel<64><<<nb, blk, 0, stream>>>(xbuf, gm, w2bb, b2b, bufY, pS, pQ, nb, nbx, F);
    finalize_kernel<<<64, 256, 0, stream>>>(pS, pQ, nb, invN, g2, be2, mr);
    norm_transpose_kernel<<<tgrid, blk, 0, stream>>>(bufY, xbuf, mr, (float*)d_out, F);
}

// Round 2
// 283.456 us; speedup vs baseline: 1.1514x; 1.1171x over previous
//
#include <hip/hip_runtime.h>
#include <math.h>

// DownConvFace: 3 stages of {mesh_conv -> BN(global stats) -> (+res) -> LeakyReLU(0.2)}
// B=4, F=50000, Cin=32/64/64, O=64, fp32 in/out.
//
// R8: conv is latency-bound (MfmaUtil 3.3%, HBM 10%, 23us wall per ~3k-cycle block).
// Restructure conv as PERSISTENT blocks with a register-staged gather pipeline:
//  - grid = resident capacity (1024 blocks CIN=32 / 512 blocks CIN=64); each block
//    loops over tiles. feat(t) -> LDS, then ISSUE gathers for t+1 into registers
//    (gidx prefetched two tiles ahead); MFMA+epilogue of t overlap the loads.
//  - weights staged in LDS once per block (tile-invariant) so the MFMA phase has
//    NO vmem reads -> vmcnt FIFO never force-drains the in-flight gathers.
//    (bias hoisted to registers for the same reason)
//  - BN partials stored per-quarter-wave directly to pS/pQ[64][4*nb] (no redS LDS
//    round-trip, one less barrier); finalize reads 4x columns.
// LDS: CIN=64: G 32KB + W 32KB = 64KB -> 2 blocks/CU (occupancy drop is expected;
// memory duty cycle is the lever). CIN=32: 17408+16KB = 33792 -> 4 blocks/CU.

typedef __attribute__((ext_vector_type(8))) short short8;
typedef __attribute__((ext_vector_type(8))) unsigned short ushort8_t;
typedef __attribute__((ext_vector_type(4))) float f32x4;

__device__ inline unsigned short f2bf(float v) {
    union { float f; unsigned u; } x; x.f = v;
    unsigned r = x.u + 0x7fffu + ((x.u >> 16) & 1u);   // RNE
    return (unsigned short)(r >> 16);
}
__device__ inline float bf2f(unsigned short u) {
    union { unsigned u; float f; } x; x.u = ((unsigned)u) << 16; return x.f;
}

// fe [B][32][F] fp32 -> fe_t [B][F][32] bf16. grid (ceil(F/64), B), block 256.
__global__ void transpose_fe_kernel(const float* __restrict__ fe,
                                    unsigned short* __restrict__ o, int F)
{
    __shared__ float tile[64 * 33];
    const int b = blockIdx.y;
    const int f0 = blockIdx.x * 64;
    const int t = threadIdx.x;
    const int lane = t & 63;
    const int w = t >> 6;
    const int f = f0 + lane;
    if (f < F) {
#pragma unroll
        for (int i = 0; i < 8; ++i) {
            const int c = w * 8 + i;
            tile[lane * 33 + c] = fe[((size_t)b * 32 + c) * F + f];
        }
    }
    __syncthreads();
    const int j = t >> 2, s = t & 3;
    const int fj = f0 + j;
    if (fj < F) {
        ushort8_t v;
#pragma unroll
        for (int i = 0; i < 8; ++i) v[i] = f2bf(tile[j * 33 + s * 8 + i]);
        *(ushort8_t*)(o + ((size_t)b * F + fj) * 32 + s * 8) = v;
    }
}

// Cast weights fp32->bf16 (flat; [O][C][4] == [O][4C], k=4c+kk).
__global__ void cast_weights_kernel(const float* __restrict__ w1,
                                    const float* __restrict__ w2a,
                                    const float* __restrict__ w2b,
                                    unsigned short* __restrict__ w1b,
                                    unsigned short* __restrict__ w2ab,
                                    unsigned short* __restrict__ w2bb)
{
    const int i = blockIdx.x * blockDim.x + threadIdx.x;
    if (i < 64 * 128) w1b[i] = f2bf(w1[i]);
    if (i < 64 * 256) { w2ab[i] = f2bf(w2a[i]); w2bb[i] = f2bf(w2b[i]); }
}

// Persistent fused mesh-conv GEMM + BN-stats. Block 256 (4 waves), 64 faces/tile.
// grid = min(nb, 1024 or 512). Y out bf16 [B*F][64]; partials to pS/pQ [64][4*nb].
template <int CIN>
__launch_bounds__(256, (CIN == 32) ? 4 : 2)
__global__ void conv_mfma_kernel(const unsigned short* __restrict__ x,  // [B][F][CIN] bf16
                                 const int*   __restrict__ gidx,        // [B][F][3]
                                 const unsigned short* __restrict__ wb, // [64][K] bf16
                                 const float* __restrict__ bias,        // [64]
                                 unsigned short* __restrict__ y,        // [B*F][64] bf16
                                 float* __restrict__ pS,                // [64][4*nb]
                                 float* __restrict__ pQ,                // [64][4*nb]
                                 int nb, int nbx, int F)
{
    constexpr int NSEG = CIN / 32;
    constexpr int K    = 4 * CIN;
    constexpr int RB   = 2 * K;                        // row bytes (pow2)
    constexpr int GB   = 64 * RB;                      // G bytes (16384 / 32768)
    constexpr int GREG = (GB > 17408) ? GB : 17408;    // G region also holds fp32 tile
    constexpr int WOFF = GREG;                         // W region (persistent weights)
    __shared__ __align__(16) unsigned char smem[GREG + GB];
    float* tile = (float*)smem;                        // [64][68] fp32 (reuses G)
    unsigned char* Wb = smem + WOFF;

    const int NBg = gridDim.x;
    const int t = threadIdx.x;
    const int j = t >> 2, s = t & 3;                   // 4 threads per face/row
    const int lane = t & 63, wv = t >> 6;
    const int l15 = lane & 15, quad = lane >> 4;
    const int kb = quad * 8;
    const int nb4 = nb * 4;

    unsigned char* grow = smem + j * RB;
    const int swz = (j & 7) << 4;
    const int nrowi = wv * 16 + l15;
    const unsigned char* nrow = smem + nrowi * RB;
    const int nswz = (nrowi & 7) << 4;

    // ---- stage weights -> LDS (once per block), same row-XOR swizzle as G ----
    {
#pragma unroll
        for (int u = 0; u < RB / 64; ++u) {
            const int qb = (s * (RB / 64) + u) * 16;   // unswizzled byte offset in row
            const ushort8_t v = *(const ushort8_t*)(wb + (size_t)j * K + qb / 2);
            *(ushort8_t*)(Wb + j * RB + (qb ^ swz)) = v;
        }
    }
    // ---- bias -> registers (tile-invariant; keeps epilogue vmem-read-free) ----
    f32x4 bias4[4];
#pragma unroll
    for (int mt = 0; mt < 4; ++mt)
        bias4[mt] = *(const f32x4*)(bias + mt * 16 + quad * 4);

    // ---- staging registers ----
    ushort8_t vc[NSEG], v0[NSEG], v1[NSEG], v2[NSEG];
    int gA0, gA1, gA2;                                 // gidx for tile tl+NBg

    int tl = blockIdx.x;
    if (tl >= nb) return;

    // prologue: gather tile tl (clamped rows; invalid faces excluded at epilogue)
    {
        const int b0 = tl / nbx;
        const int f0 = (tl - b0 * nbx) * 64;
        const int fc = min(f0 + j, F - 1);
        const int* gp = gidx + ((size_t)b0 * F + fc) * 3;
        const int g0 = gp[0], g1 = gp[1], g2 = gp[2];
        const unsigned short* xb = x + (size_t)b0 * F * CIN;
        const unsigned short* pc = xb + (size_t)fc * CIN;
        const unsigned short* p0 = xb + (size_t)g0 * CIN;
        const unsigned short* p1 = xb + (size_t)g1 * CIN;
        const unsigned short* p2 = xb + (size_t)g2 * CIN;
#pragma unroll
        for (int i = 0; i < NSEG; ++i) {
            const int c0 = (i * 4 + s) * 8;
            vc[i] = *(const ushort8_t*)(pc + c0);
            v0[i] = *(const ushort8_t*)(p0 + c0);
            v1[i] = *(const ushort8_t*)(p1 + c0);
            v2[i] = *(const ushort8_t*)(p2 + c0);
        }
    }
    {   // prefetch gidx one tile ahead
        const int tn = min(tl + NBg, nb - 1);
        const int bn = tn / nbx;
        const int fn = min((tn - bn * nbx) * 64 + j, F - 1);
        const int* gp = gidx + ((size_t)bn * F + fn) * 3;
        gA0 = gp[0]; gA1 = gp[1]; gA2 = gp[2];
    }

    for (; tl < nb; tl += NBg) {
        const int b  = tl / nbx;
        const int f0 = (tl - b * nbx) * 64;

        // ---- feat(cur regs) -> LDS G (waits only the gathers; swizzled write) ----
#pragma unroll
        for (int i = 0; i < NSEG; ++i) {
            const int c0 = (i * 4 + s) * 8;
            unsigned short feat[32];
#pragma unroll
            for (int q = 0; q < 8; ++q) {
                const float ctr = bf2f(vc[i][q]);
                const float a   = bf2f(v0[i][q]);
                const float bb  = bf2f(v1[i][q]);
                const float cc  = bf2f(v2[i][q]);
                const float su  = a + bb + cc;
                const float dd  = fabsf(a - bb) + fabsf(bb - cc) + fabsf(cc - a);
                const float mm  = fmaxf(a, fmaxf(bb, cc));
                feat[4 * q + 0] = f2bf(ctr);
                feat[4 * q + 1] = f2bf(su);
                feat[4 * q + 2] = f2bf(dd);
                feat[4 * q + 3] = f2bf(mm);
            }
#pragma unroll
            for (int q4 = 0; q4 < 4; ++q4) {
                const int qb = 8 * c0 + 16 * q4;
                *(ushort8_t*)(grow + (qb ^ swz)) = *(ushort8_t*)(feat + q4 * 8);
            }
        }

        // ---- issue gathers for tile tl+NBg into regs; they fly over MFMA+epilogue ----
        {
            const int tn = min(tl + NBg, nb - 1);
            const int bn = tn / nbx;
            const int fcn = min((tn - bn * nbx) * 64 + j, F - 1);
            const unsigned short* xb = x + (size_t)bn * F * CIN;
            const unsigned short* pc = xb + (size_t)fcn * CIN;
            const unsigned short* p0 = xb + (size_t)gA0 * CIN;
            const unsigned short* p1 = xb + (size_t)gA1 * CIN;
            const unsigned short* p2 = xb + (size_t)gA2 * CIN;
#pragma unroll
            for (int i = 0; i < NSEG; ++i) {
                const int c0 = (i * 4 + s) * 8;
                vc[i] = *(const ushort8_t*)(pc + c0);
                v0[i] = *(const ushort8_t*)(p0 + c0);
                v1[i] = *(const ushort8_t*)(p1 + c0);
                v2[i] = *(const ushort8_t*)(p2 + c0);
            }
            // gidx two tiles ahead
            const int t2 = min(tl + 2 * NBg, nb - 1);
            const int b2 = t2 / nbx;
            const int f2 = min((t2 - b2 * nbx) * 64 + j, F - 1);
            const int* gp = gidx + ((size_t)b2 * F + f2) * 3;
            gA0 = gp[0]; gA1 = gp[1]; gA2 = gp[2];
        }
        __syncthreads();                               // B1: G (and W, first iter) ready

        // ---- MFMA: pure LDS reads (G + W), no vmem -> gathers stay in flight ----
        f32x4 acc[4];
#pragma unroll
        for (int mt = 0; mt < 4; ++mt) acc[mt] = (f32x4){0.f, 0.f, 0.f, 0.f};
#pragma unroll
        for (int ks = 0; ks < K; ks += 32) {
            const int cb = 2 * (ks + kb);
            const short8 bfr = *(const short8*)(nrow + (cb ^ nswz));
#pragma unroll
            for (int mt = 0; mt < 4; ++mt) {
                const int ar = mt * 16 + l15;
                const short8 afr = *(const short8*)(Wb + ar * RB + (cb ^ ((ar & 7) << 4)));
                acc[mt] = __builtin_amdgcn_mfma_f32_16x16x32_bf16(afr, bfr, acc[mt], 0, 0, 0);
            }
        }
        __syncthreads();                               // B2: G dead -> reuse as tile

        // ---- epilogue: acc -> LDS tile [face][68] (+bias from regs) ----
        {
            const int face = wv * 16 + l15;
#pragma unroll
            for (int mt = 0; mt < 4; ++mt) {
                const int ob = mt * 16 + quad * 4;
                *(f32x4*)(tile + face * 68 + ob) = acc[mt] + bias4[mt];
            }
        }
        __syncthreads();                               // B3: tile ready
        {   // pass A: per-quarter-wave channel partials straight to global
            const int o = t & 63, g = t >> 6;
            float S = 0.f, Q = 0.f;
#pragma unroll
            for (int i = 0; i < 16; ++i) {
                const int f = g + 4 * i;
                if (f0 + f < F) {
                    const float v = tile[f * 68 + o];
                    S += v; Q += v * v;
                }
            }
            pS[(size_t)o * nb4 + 4 * tl + g] = S;
            pQ[(size_t)o * nb4 + 4 * tl + g] = Q;
        }
        {   // pass B: coalesced bf16 Y store
            const int seg = s;
            const int f = f0 + j;
            if (f < F) {
                ushort8_t u0, u1;
#pragma unroll
                for (int ii = 0; ii < 8; ++ii) u0[ii] = f2bf(tile[j * 68 + seg * 16 + ii]);
#pragma unroll
                for (int ii = 0; ii < 8; ++ii) u1[ii] = f2bf(tile[j * 68 + seg * 16 + 8 + ii]);
                unsigned short* yp = y + ((size_t)b * F + f) * 64 + seg * 16;
                *(ushort8_t*)yp       = u0;
                *(ushort8_t*)(yp + 8) = u1;
            }
        }
        __syncthreads();                               // B4: tile dead before next feat
    }
}

// grid 64 (one block per channel), 256 threads. Contiguous reads of pS/pQ[o][0..nb4).
__global__ void finalize_kernel(const float* __restrict__ pS, const float* __restrict__ pQ,
                                int nb4, float invN,
                                const float* __restrict__ gamma,
                                const float* __restrict__ beta,
                                float* __restrict__ mr)
{
    __shared__ float rs_[256], rq_[256];
    const int o = blockIdx.x, t = threadIdx.x;
    float S = 0.f, Q = 0.f;
    for (int jj = t; jj < nb4; jj += 256) {
        S += pS[(size_t)o * nb4 + jj];
        Q += pQ[(size_t)o * nb4 + jj];
    }
    rs_[t] = S; rq_[t] = Q;
    __syncthreads();
#pragma unroll
    for (int s = 128; s > 0; s >>= 1) {
        if (t < s) { rs_[t] += rs_[t + s]; rq_[t] += rq_[t + s]; }
        __syncthreads();
    }
    if (t == 0) {
        const float mu  = rs_[0] * invN;
        const float var = rq_[0] * invN - mu * mu;
        const float rsg = rsqrtf(var + 1e-5f);
        const float sc  = gamma[o] * rsg;
        mr[o]      = sc;
        mr[64 + o] = fmaf(-sc, mu, beta[o]);
    }
}

// BN+res+lrelu, face-major bf16 -> bf16. One 16B group of 8 channels per thread.
__global__ void norm_kernel(const unsigned short* __restrict__ y,   // [M][64] bf16
                            const unsigned short* __restrict__ res, // [M][64] bf16 or null
                            const float* __restrict__ mr,
                            unsigned short* __restrict__ out,       // [M][64] bf16
                            int N8)
{
    const int tid = blockIdx.x * blockDim.x + threadIdx.x;
    if (tid >= N8) return;
    const int c0 = (tid & 7) * 8;
    const ushort8_t yv = *(const ushort8_t*)(y + (size_t)tid * 8);
    const f32x4 scA = *(const f32x4*)(mr + c0);
    const f32x4 scB = *(const f32x4*)(mr + c0 + 4);
    const f32x4 shA = *(const f32x4*)(mr + 64 + c0);
    const f32x4 shB = *(const f32x4*)(mr + 64 + c0 + 4);
    float r[8];
#pragma unroll
    for (int i = 0; i < 4; ++i) {
        r[i]     = fmaf(bf2f(yv[i]),     scA[i], shA[i]);
        r[4 + i] = fmaf(bf2f(yv[4 + i]), scB[i], shB[i]);
    }
    if (res) {
        const ushort8_t u = *(const ushort8_t*)(res + (size_t)tid * 8);
#pragma unroll
        for (int i = 0; i < 8; ++i) r[i] += bf2f(u[i]);
    }
    ushort8_t o;
#pragma unroll
    for (int i = 0; i < 8; ++i) {
        const float v = r[i];
        o[i] = f2bf(v >= 0.f ? v : 0.2f * v);
    }
    *(ushort8_t*)(out + (size_t)tid * 8) = o;
}

// Final BN+res+lrelu fused with transpose [B*F][64] -> [B][64][F] fp32 (d_out).
__global__ void norm_transpose_kernel(const unsigned short* __restrict__ y,   // bf16
                                      const unsigned short* __restrict__ res, // bf16
                                      const float* __restrict__ mr,
                                      float* __restrict__ out, int F)
{
    __shared__ float tile[64 * 65];
    const int b = blockIdx.y, f0 = blockIdx.x * 64, t = threadIdx.x;
    const int j = t >> 2, s = t & 3;
    const int f = f0 + j;
    if (f < F) {
        const size_t row = ((size_t)b * F + f) * 64;
#pragma unroll
        for (int i = 0; i < 4; ++i) {
            const int c0 = (i * 4 + s) * 4;
            const ushort4 yv = *(const ushort4*)(y + row + c0);
            const f32x4 sc = *(const f32x4*)(mr + c0);
            const f32x4 sh = *(const f32x4*)(mr + 64 + c0);
            const ushort4 u = *(const ushort4*)(res + row + c0);
            const float yf[4] = {bf2f(yv.x), bf2f(yv.y), bf2f(yv.z), bf2f(yv.w)};
            const float rv[4] = {bf2f(u.x), bf2f(u.y), bf2f(u.z), bf2f(u.w)};
#pragma unroll
            for (int q = 0; q < 4; ++q) {
                float vv = fmaf(yf[q], sc[q], sh[q]) + rv[q];
                vv = vv >= 0.f ? vv : 0.2f * vv;
                tile[(c0 + q) * 65 + j] = vv;
            }
        }
    }
    __syncthreads();
    const int o = t >> 2;
    float* ob = out + ((size_t)b * 64 + o) * F + f0;
#pragma unroll
    for (int i = 0; i < 4; ++i) {
        const int fs = (i * 4 + s) * 4;
        if (f0 + fs < F) {
            f32x4 v;
#pragma unroll
            for (int q = 0; q < 4; ++q) v[q] = tile[o * 65 + fs + q];
            *(f32x4*)(ob + fs) = v;
        }
    }
}

extern "C" void kernel_launch(void* const* d_in, const int* in_sizes, int n_in,
                              void* d_out, int out_size, void* d_ws, size_t ws_size,
                              hipStream_t stream)
{
    const float* fe  = (const float*)d_in[0];
    const int*   gm  = (const int*)d_in[1];
    const float* w1  = (const float*)d_in[2];
    const float* b1  = (const float*)d_in[3];
    const float* w2a = (const float*)d_in[4];
    const float* b2a = (const float*)d_in[5];
    const float* w2b = (const float*)d_in[6];
    const float* b2b = (const float*)d_in[7];
    const float* g0  = (const float*)d_in[8];
    const float* be0 = (const float*)d_in[9];
    const float* g1  = (const float*)d_in[10];
    const float* be1 = (const float*)d_in[11];
    const float* g2  = (const float*)d_in[12];
    const float* be2 = (const float*)d_in[13];

    const int B = 4, O = 64;
    const int F = in_sizes[0] / (B * 32);
    const int M = B * F;
    const float invN = 1.0f / (float)M;
    const int nbx = (F + 63) / 64;
    const int nb  = nbx * B;
    const int nb4 = nb * 4;

    // Workspace: bufY bf16 [M][64] + xbuf bf16 [M][64] + partials + weights.
    unsigned short* bufY = (unsigned short*)d_ws;
    unsigned short* xbuf = bufY + (size_t)M * O;
    float* pS   = (float*)(xbuf + (size_t)M * O);       // [64][4*nb]
    float* pQ   = pS + (size_t)64 * nb4;                // [64][4*nb]
    float* mr   = pQ + (size_t)64 * nb4;                // [2][64]
    unsigned short* w1b  = (unsigned short*)(mr + 128); // [64][128]
    unsigned short* w2ab = w1b + 64 * 128;              // [64][256]
    unsigned short* w2bb = w2ab + 64 * 256;             // [64][256]
    unsigned short* fe_t = (unsigned short*)d_out;      // [B][F][32] bf16, dead after conv1

    dim3 blk(256);
    dim3 tgrid(nbx, B);
    const int N8 = M * 8;
    dim3 ngrid((N8 + 255) / 256);
    const int g32 = (nb < 1024) ? nb : 1024;            // 4 blocks/CU resident
    const int g64 = (nb < 512)  ? nb : 512;             // 2 blocks/CU resident

    transpose_fe_kernel<<<tgrid, blk, 0, stream>>>(fe, fe_t, F);
    cast_weights_kernel<<<64, 256, 0, stream>>>(w1, w2a, w2b, w1b, w2ab, w2bb);

    // ---- Stage 1 ----
    conv_mfma_kernel<32><<<g32, blk, 0, stream>>>(fe_t, gm, w1b, b1, bufY, pS, pQ, nb, nbx, F);
    finalize_kernel<<<64, 256, 0, stream>>>(pS, pQ, nb4, invN, g0, be0, mr);
    norm_kernel<<<ngrid, blk, 0, stream>>>(bufY, nullptr, mr, xbuf, N8);

    // ---- Stage 2 ----
    conv_mfma_kernel<64><<<g64, blk, 0, stream>>>(xbuf, gm, w2ab, b2a, bufY, pS, pQ, nb, nbx, F);
    finalize_kernel<<<64, 256, 0, stream>>>(pS, pQ, nb4, invN, g1, be1, mr);
    norm_kernel<<<ngrid, blk, 0, stream>>>(bufY, xbuf, mr, xbuf, N8);

    // ---- Stage 3 ----
    conv_mfma_kernel<64><<<g64, blk, 0, stream>>>(xbuf, gm, w2bb, b2b, bufY, pS, pQ, nb, nbx, F);
    finalize_kernel<<<64, 256, 0, stream>>>(pS, pQ, nb4, invN, g2, be2, mr);
    norm_transpose_kernel<<<tgrid, blk, 0, stream>>>(bufY, xbuf, mr, (float*)d_out, F);
}